// Round 2
// baseline (567.669 us; speedup 1.0000x reference)
//
#include <hip/hip_runtime.h>

// SNN forward. Round 2: per-XCD privatized hid accumulators (8 copies,
// copy = blockIdx%8 so each copy is only touched by one XCD -> atomic lines
// stay dirty in that XCD's L2, killing the cross-XCD 32B-per-atomic
// write-through seen in round 1), + LDS-privatized motor scatter.

#define N_SENS 10000
#define N_HID  400000
#define N_MOT  1000
#define NB_HM  256   // blocks for motor scatter (partials buffers)

__global__ void lif_kernel(const float* __restrict__ inp,
                           const float* __restrict__ mem_in,
                           float* __restrict__ spk,
                           float scale, int n) {
    int i = blockIdx.x * blockDim.x + threadIdx.x;
    if (i < n) {
        float m = 0.9f * mem_in[i] + scale * inp[i];
        spk[i] = (m > 1.0f) ? 1.0f : 0.0f;
    }
}

// out_copy[blockIdx%n_copies][post[e]] += scale * w[e] * spikes[pre[e]]
__global__ void scatter_priv(const int* __restrict__ pre,
                             const int* __restrict__ post,
                             const float* __restrict__ w,
                             const float* __restrict__ spikes,
                             float* __restrict__ copies, int n_copies,
                             float scale, int n_edges) {
    int e = blockIdx.x * blockDim.x + threadIdx.x;
    if (e >= n_edges) return;
    float s = spikes[pre[e]];
    if (s != 0.0f) {
        float* dst = copies + (size_t)(blockIdx.x % n_copies) * N_HID;
        atomicAdd(&dst[post[e]], scale * w[e] * s);
    }
}

// hid_spk[i] = LIF( sum_c copies[c][i] )
__global__ void reduce_lif_hidden(const float* __restrict__ copies, int n_copies,
                                  const float* __restrict__ mem,
                                  float* __restrict__ spk) {
    int i = blockIdx.x * blockDim.x + threadIdx.x;
    if (i >= N_HID) return;
    float sum = 0.0f;
    for (int c = 0; c < n_copies; ++c) sum += copies[(size_t)c * N_HID + i];
    float m = 0.9f * mem[i] + 5.0f * sum;
    spk[i] = (m > 1.0f) ? 1.0f : 0.0f;
}

// motor scatter: per-block LDS accumulator (1000 floats), then coalesced
// per-block partial write -- no global atomics at all.
__global__ void scatter_motor(const int* __restrict__ pre,
                              const int* __restrict__ post,
                              const float* __restrict__ w,
                              const float* __restrict__ spikes,
                              float* __restrict__ partials, int n_edges) {
    __shared__ float acc[N_MOT];
    for (int j = threadIdx.x; j < N_MOT; j += blockDim.x) acc[j] = 0.0f;
    __syncthreads();
    for (int e = blockIdx.x * blockDim.x + threadIdx.x; e < n_edges;
         e += gridDim.x * blockDim.x) {
        float s = spikes[pre[e]];
        if (s != 0.0f) atomicAdd(&acc[post[e]], w[e] * s);
    }
    __syncthreads();
    float* out = partials + (size_t)blockIdx.x * N_MOT;
    for (int j = threadIdx.x; j < N_MOT; j += blockDim.x) out[j] = acc[j];
}

__global__ void reduce_lif_motor(const float* __restrict__ partials, int nb,
                                 const float* __restrict__ mem,
                                 float* __restrict__ out) {
    int m = blockIdx.x * blockDim.x + threadIdx.x;
    if (m >= N_MOT) return;
    float sum = 0.0f;
    for (int b = 0; b < nb; ++b) sum += partials[(size_t)b * N_MOT + m];
    float v = 0.9f * mem[m] + 20.0f * sum;
    out[m] = (v > 1.0f) ? 1.0f : 0.0f;
}

extern "C" void kernel_launch(void* const* d_in, const int* in_sizes, int n_in,
                              void* d_out, int out_size, void* d_ws, size_t ws_size,
                              hipStream_t stream) {
    const float* sensory_input = (const float*)d_in[0];
    const float* sensory_mem   = (const float*)d_in[1];
    const float* hidden_mem    = (const float*)d_in[2];
    const float* motor_mem     = (const float*)d_in[3];
    const float* hidden_prev   = (const float*)d_in[4];
    const float* w_sh          = (const float*)d_in[5];
    const float* w_hh          = (const float*)d_in[6];
    const float* w_hm          = (const float*)d_in[7];
    const int*   sh_pre        = (const int*)d_in[8];
    const int*   sh_post       = (const int*)d_in[9];
    const int*   hh_pre        = (const int*)d_in[10];
    const int*   hh_post       = (const int*)d_in[11];
    const int*   hm_pre        = (const int*)d_in[12];
    const int*   hm_post       = (const int*)d_in[13];
    const int e_sh = in_sizes[5];
    const int e_hh = in_sizes[6];
    const int e_hm = in_sizes[7];

    // ws layout (floats): [copies n_copies*400K][partials NB_HM*1000]
    //                     [sens_spk 10K][hid_spk 400K]
    size_t floats_avail = ws_size / sizeof(float);
    size_t fixed = (size_t)N_SENS + N_HID + (size_t)NB_HM * N_MOT;
    long avail_for_copies = (long)floats_avail - (long)fixed;
    int n_copies = (int)(avail_for_copies / N_HID);
    if (n_copies > 8) n_copies = 8;
    if (n_copies < 1) n_copies = 1;

    float* ws       = (float*)d_ws;
    float* copies   = ws;
    float* partials = copies + (size_t)n_copies * N_HID;
    float* sens_spk = partials + (size_t)NB_HM * N_MOT;
    float* hid_spk  = sens_spk + N_SENS;

    // zero copies + partials in one contiguous memset
    hipMemsetAsync(copies, 0,
                   ((size_t)n_copies * N_HID + (size_t)NB_HM * N_MOT) * sizeof(float),
                   stream);

    const int B = 256;
    lif_kernel<<<(N_SENS + B - 1) / B, B, 0, stream>>>(sensory_input, sensory_mem,
                                                       sens_spk, 5.0f, N_SENS);
    scatter_priv<<<(e_sh + B - 1) / B, B, 0, stream>>>(sh_pre, sh_post, w_sh,
                                                       sens_spk, copies, n_copies,
                                                       1.0f, e_sh);
    scatter_priv<<<(e_hh + B - 1) / B, B, 0, stream>>>(hh_pre, hh_post, w_hh,
                                                       hidden_prev, copies, n_copies,
                                                       0.5f, e_hh);
    reduce_lif_hidden<<<(N_HID + B - 1) / B, B, 0, stream>>>(copies, n_copies,
                                                             hidden_mem, hid_spk);
    scatter_motor<<<NB_HM, B, 0, stream>>>(hm_pre, hm_post, w_hm,
                                           hid_spk, partials, e_hm);
    reduce_lif_motor<<<(N_MOT + B - 1) / B, B, 0, stream>>>(partials, NB_HM,
                                                            motor_mem, (float*)d_out);
}